// Round 3
// baseline (348.275 us; speedup 1.0000x reference)
//
#include <hip/hip_runtime.h>

#define B_ 4
#define S_ 4096
#define E_ 1024
#define D_ 64

typedef __attribute__((ext_vector_type(8))) short short8;
typedef __attribute__((ext_vector_type(4))) float floatx4;
typedef __attribute__((ext_vector_type(4))) unsigned int uint4v;

__device__ __forceinline__ floatx4 mfma_bf16(short8 a, short8 b, floatx4 c) {
    return __builtin_amdgcn_mfma_f32_16x16x32_bf16(a, b, c, 0, 0, 0);
}

// fp32 -> bf16 round-to-nearest-even (scalar)
__device__ __forceinline__ short f2bf(float f) {
    unsigned u = __builtin_bit_cast(unsigned, f);
    u = (u + 0x7FFFu + ((u >> 16) & 1u)) >> 16;
    return (short)u;
}

// packed pair fp32 -> bf16x2 (a low 16, b high 16), manual RNE
__device__ __forceinline__ unsigned pk2bf(float a, float b) {
    unsigned ua = __builtin_bit_cast(unsigned, a);
    unsigned ub = __builtin_bit_cast(unsigned, b);
    ua = (ua + 0x7FFFu + ((ua >> 16) & 1u)) >> 16;
    ub = (ub + 0x7FFFu + ((ub >> 16) & 1u)) & 0xFFFF0000u;
    return ua | ub;
}

// async global -> LDS DMA, 16 B per lane. LDS dest = wave-uniform base + lane*16
// (m104); global src is per-lane (enables swizzled staging, m173).
__device__ __forceinline__ void gload_lds16(const void* g, void* l) {
    __builtin_amdgcn_global_load_lds(
        (const __attribute__((address_space(1))) void*)g,
        (__attribute__((address_space(3))) void*)l, 16, 0, 0);
}

// Kernel 1: convert+transpose weights fp32 [E,D] -> bf16 WT [3][D][E]; zero flag.
__global__ __launch_bounds__(256) void prep_kernel(
    const float* __restrict__ Wq, const float* __restrict__ Wk, const float* __restrict__ Wv,
    short* __restrict__ WT, int* __restrict__ flag)
{
    int tid = blockIdx.x * 256 + threadIdx.x;   // 768*256 = 196608 = 3*65536
    if (tid == 0) *flag = 0;
    int mat = tid >> 16;
    int rem = tid & 65535;
    const float* W = (mat == 0) ? Wq : ((mat == 1) ? Wk : Wv);
    int n = rem >> 10, k = rem & 1023;
    WT[mat * 65536 + n * E_ + k] = f2bf(W[k * D_ + n]);
}

// Kernel 2: fused QKV projection, wave-autonomous deep-pipelined GEMM.
//   R2 post-mortem: the barrier-per-step structure drained vmcnt(0) every 16KB
//   -> ~2KB/CU in flight -> 1.35 TB/s. Fix (T4): no barriers at all. Each wave
//   owns 16 rows x K=1024 (no K-split, no cross-wave sharing). A staged via
//   global_load_lds (2 x 1KB per 32-k step, XOR-swizzled global src + linear
//   LDS dest), 4 bufs, prefetch distance 3, gated by counted
//   s_waitcnt vmcnt(12) only (stage s is always >=14 instrs deep at consume
//   => complete; W-reg deps are compiler-tracked). W ([64][1024] bf16/mat,
//   L2-hot from prep) read direct with depth-2 register prefetch.
//   grid (256,3) = 768 blocks = exactly 3/CU -> all resident at t=0, no tail.
//   Mask check folded in after the GEMM loop (overlaps straggler BW).
__global__ __launch_bounds__(256, 4) void proj_kernel(
    const float* __restrict__ Qm, const float* __restrict__ Km, const float* __restrict__ Vm,
    const short* __restrict__ WT,
    const float* __restrict__ bq, const float* __restrict__ bk, const float* __restrict__ bv,
    short* __restrict__ qs, short* __restrict__ ks, short* __restrict__ vT,
    const int4* __restrict__ mask4, int* __restrict__ flag)
{
    __shared__ __align__(16) char smem[32768];   // 4 waves x 4 bufs x 2KB

    const int mat = blockIdx.y;            // 0:q 1:k 2:v
    const int bx  = blockIdx.x;            // 0..255
    const int tid = threadIdx.x;
    const int wv = tid >> 6, lane = tid & 63;
    const int quad = lane >> 4, c16 = lane & 15;
    const int m0 = bx * 64 + wv * 16;      // wave's 16 output rows

    const float* X    = (mat == 0) ? Qm : ((mat == 1) ? Km : Vm);
    const float* bias = (mat == 0) ? bq : ((mat == 1) ? bk : bv);
    const short* Wt   = WT + mat * 65536;

    // ---- A staging addresses. Tile per step: [16 rows][32 k fp32] = [16][128B].
    // Instr j in {0,1}: lane l -> row j*8 + (l>>3), LDS chunk l&7 holds global
    // chunk (l&7)^(row&7)  (row&7 == (l>>3)&7 for both j).
    const int srow = lane >> 3;                          // 0..7
    const int cs   = (lane & 7) ^ srow;                  // swizzled global chunk
    const char* gA = (const char*)X + (size_t)(m0 + srow) * 4096 + (size_t)cs * 16;
    char* lds_w = smem + wv * 8192;                      // + buf*2048 + j*1024

    #define PSTAGE(s) do {                               \
        const char* a0_ = gA + (size_t)(s) * 128;        \
        char* lb_ = lds_w + ((s) & 3) * 2048;            \
        gload_lds16(a0_,         lb_);                   \
        gload_lds16(a0_ + 32768, lb_ + 1024);            \
    } while (0)

    // ---- W fragment loads (L2-direct): frag f = rows f*16+c16, k = s*32+quad*8
    const short* wbase = Wt + (size_t)c16 * 1024 + quad * 8;
    #define WLOAD(s, dst) do {                           \
        const short* wp_ = wbase + (s) * 32;             \
        dst[0] = *(const short8*)(wp_);                  \
        dst[1] = *(const short8*)(wp_ + 16384);          \
        dst[2] = *(const short8*)(wp_ + 32768);          \
        dst[3] = *(const short8*)(wp_ + 49152);          \
    } while (0)

    floatx4 acc[4];
    #pragma unroll
    for (int f = 0; f < 4; ++f) acc[f] = (floatx4){0.f, 0.f, 0.f, 0.f};
    short8 wA[4], wB[4];

    PSTAGE(0); PSTAGE(1); PSTAGE(2);       // 6 vm-instr
    WLOAD(0, wA); WLOAD(1, wB);            // 8 vm-instr

    // LDS read: lane reads row c16, global chunks 2q, 2q+1 -> LDS chunks ^(c16&7)
    const int am = c16 & 7;
    const char* ra = smem + wv * 8192 + c16 * 128;
    const int off0 = ((2 * quad)     ^ am) * 16;
    const int off1 = ((2 * quad + 1) ^ am) * 16;

    #pragma unroll 2
    for (int s = 0; s < 32; ++s) {
        // stage s complete when <=12 vm ops outstanding (it is >=14 deep here);
        // memory clobber keeps the LDS reads below from hoisting above it.
        asm volatile("s_waitcnt vmcnt(12)" ::: "memory");
        if (s + 3 < 32) PSTAGE(s + 3);     // distance 3, buf (s+3)&3 != s&3

        const char* rb = ra + (s & 3) * 2048;
        float4 fa = *(const float4*)(rb + off0);
        float4 fb = *(const float4*)(rb + off1);
        uint4v uv;
        uv[0] = pk2bf(fa.x, fa.y); uv[1] = pk2bf(fa.z, fa.w);
        uv[2] = pk2bf(fb.x, fb.y); uv[3] = pk2bf(fb.z, fb.w);
        short8 a = __builtin_bit_cast(short8, uv);

        if (s & 1) {
            #pragma unroll
            for (int f = 0; f < 4; ++f) acc[f] = mfma_bf16(a, wB[f], acc[f]);
            if (s + 2 < 32) WLOAD(s + 2, wB);
        } else {
            #pragma unroll
            for (int f = 0; f < 4; ++f) acc[f] = mfma_bf16(a, wA[f], acc[f]);
            if (s + 2 < 32) WLOAD(s + 2, wA);
        }
    }
    #undef PSTAGE
    #undef WLOAD

    // ---- epilogue (wave-autonomous: full K summed, no combine, no barrier)
    const float scale = (mat == 0) ? (0.125f * 1.4426950408889634f) : 1.0f;
    #pragma unroll
    for (int f = 0; f < 4; ++f) {
        float bb = bias[f * 16 + c16];
        #pragma unroll
        for (int r = 0; r < 4; ++r) {
            int m = m0 + quad * 4 + r;             // C/D: row = quad*4+r, col = c16
            float v = (acc[f][r] + bb) * scale;
            short h = f2bf(v);
            if (mat == 0)      qs[(size_t)m * D_ + f * 16 + c16] = h;
            else if (mat == 1) ks[(size_t)m * D_ + f * 16 + c16] = h;
            else vT[((size_t)((m >> 12) * D_ + f * 16 + c16)) * S_ + (m & (S_ - 1))] = h;
        }
    }

    // ---- mask check slice (64MB spread over all 768 blocks, overlaps tail)
    {
        int btid = (mat * 256 + bx) * 256 + tid;
        const int stride = 768 * 256;
        int found = 0;
        for (int i = btid; i < (S_ * S_ / 4); i += stride) {
            int4 v = mask4[i];
            found |= (v.x == 0) | (v.y == 0) | (v.z == 0) | (v.w == 0);
        }
        if (found) atomicOr(flag, 1);
    }
}

// Kernel 3: flash attention v3 (unchanged this round for clean attribution).
// Block = 512 thr = 8 waves = 4 q-subtiles (16 rows) x 2 K-halves over a 64-row
// q-tile. K staged in LDS (dbuf, pitch-72 pad) with a single-barrier pipeline;
// V prefetched right after the barrier so its L2 latency hides under
// S^T + softmax + P staging. Batches pinned to XCD pairs via bid swizzle.
__global__ __launch_bounds__(512, 2) void flash_kernel(
    const short* __restrict__ qs, const short* __restrict__ ks,
    const short* __restrict__ vT, const int* __restrict__ mask,
    const int* __restrict__ flag, float* __restrict__ out)
{
    __shared__ __align__(16) char smem[35840];
    short* kst = (short*)smem;          // [2 dbuf][2 kw][32 rows][72] shorts = 18432 B
    short* pst = kst + 9216;            // [8 waves][16 rows][40] shorts = 10240 B

    const int bid = blockIdx.x;                     // 256 blocks
    const int b  = (bid & 7) >> 1;                  // batch -> XCD pair
    const int qt = ((bid >> 3) << 1) | (bid & 1);   // 0..63
    const int tid = threadIdx.x;
    const int w = tid >> 6;                         // 0..7
    const int qw = w & 3, kw = w >> 2;
    const int lane = tid & 63;
    const int quad = lane >> 4, c16 = lane & 15;
    const int m0 = qt * 64 + qw * 16;

    const short* qrow = qs + (size_t)(b * S_ + m0 + c16) * D_ + quad * 8;
    short8 aq0 = *(const short8*)(qrow);
    short8 aq1 = *(const short8*)(qrow + 32);

    const short* kbase = ks + (size_t)b * S_ * D_ + (size_t)kw * 2048 * D_;
    const short* vbase = vT + (size_t)b * D_ * S_ + kw * 2048;

    const int srow = (w & 3) * 8 + (lane >> 3);
    const int schunk = lane & 7;
    const short* gstage = kbase + srow * D_ + schunk * 8;
    short* lstage = kst + kw * 2304 + srow * 72 + schunk * 8;   // +buf*4608

    floatx4 O[4];
    #pragma unroll
    for (int f = 0; f < 4; ++f) O[f] = (floatx4){0.f, 0.f, 0.f, 0.f};
    float lsum = 0.f;

    const int anyz = *flag;
    short* pw = pst + w * 640;
    short8 g = *(const short8*)(gstage);   // kt = 0

    for (int kt = 0; kt < 64; ++kt) {
        const int buf = kt & 1;
        *(short8*)(lstage + buf * 4608) = g;          // stage tile kt
        short8 gn = g;
        if (kt < 63) gn = *(const short8*)(gstage + (size_t)(kt + 1) * 2048);
        __syncthreads();                               // tile kt visible to all

        const int key0 = kt * 32;

        // V prefetch: addresses depend only on kt
        short8 vv[4];
        #pragma unroll
        for (int f = 0; f < 4; ++f)
            vv[f] = *(const short8*)(vbase + (size_t)(f * 16 + c16) * S_ + key0 + quad * 8);

        const short* kt_lds = kst + buf * 4608 + kw * 2304;

        // S^T (32 keys x 16 q): A = K frags (LDS), B = Q frags
        floatx4 s[2];
        #pragma unroll
        for (int f = 0; f < 2; ++f) {
            const short* krow = kt_lds + (f * 16 + c16) * 72 + quad * 8;
            short8 ka0 = *(const short8*)(krow);
            short8 ka1 = *(const short8*)(krow + 32);
            floatx4 t = (floatx4){0.f, 0.f, 0.f, 0.f};
            t = mfma_bf16(ka0, aq0, t);
            t = mfma_bf16(ka1, aq1, t);
            s[f] = t;
        }

        if (anyz) {   // not taken for the all-ones bench mask
            #pragma unroll
            for (int f = 0; f < 2; ++f)
                #pragma unroll
                for (int r = 0; r < 4; ++r)
                    if (mask[(size_t)(m0 + c16) * S_ +
                             kw * 2048 + key0 + f * 16 + quad * 4 + r] == 0)
                        s[f][r] = -__builtin_inff();
        }

        // P = exp2(s): per-lane row-sum (q = c16); pack to bf16, stage in LDS
        #pragma unroll
        for (int f = 0; f < 2; ++f) {
            float p0 = exp2f(s[f][0]), p1 = exp2f(s[f][1]);
            float p2 = exp2f(s[f][2]), p3 = exp2f(s[f][3]);
            lsum += (p0 + p1) + (p2 + p3);
            int2 pk = make_int2((int)pk2bf(p0, p1), (int)pk2bf(p2, p3));
            *(int2*)(pw + c16 * 40 + f * 16 + quad * 4) = pk;
        }

        // reload P in A-layout (wave-private, DS in-order => no barrier)
        short8 pa = *(const short8*)(pw + c16 * 40 + quad * 8);

        // O += P @ V_tile
        #pragma unroll
        for (int f = 0; f < 4; ++f) O[f] = mfma_bf16(pa, vv[f], O[f]);
        g = gn;
    }

    lsum += __shfl_xor(lsum, 16);
    lsum += __shfl_xor(lsum, 32);

    __syncthreads();
    float* of = (float*)smem;                  // [2][64][68] fp32
    float* lw = (float*)(smem + 34816);        // [2][64]
    #pragma unroll
    for (int f = 0; f < 4; ++f)
        #pragma unroll
        for (int r = 0; r < 4; ++r)
            of[(kw * 64 + qw * 16 + quad * 4 + r) * 68 + f * 16 + c16] = O[f][r];
    if (quad == 0) lw[kw * 64 + qw * 16 + c16] = lsum;
    __syncthreads();

    {
        const int q = tid >> 3;                // 0..63
        const int col0 = (tid & 7) * 8;        // 0..56
        const float inv = 1.0f / (lw[q] + lw[64 + q]);
        const float* r0 = &of[q * 68 + col0];
        const float* r1 = &of[(64 + q) * 68 + col0];
        float4 o0, o1;
        o0.x = (r0[0] + r1[0]) * inv; o0.y = (r0[1] + r1[1]) * inv;
        o0.z = (r0[2] + r1[2]) * inv; o0.w = (r0[3] + r1[3]) * inv;
        o1.x = (r0[4] + r1[4]) * inv; o1.y = (r0[5] + r1[5]) * inv;
        o1.z = (r0[6] + r1[6]) * inv; o1.w = (r0[7] + r1[7]) * inv;
        float* op = out + ((size_t)(b * S_ + qt * 64 + q)) * 64 + col0;
        *(float4*)(op) = o0;
        *(float4*)(op + 4) = o1;
    }
}

extern "C" void kernel_launch(void* const* d_in, const int* in_sizes, int n_in,
                              void* d_out, int out_size, void* d_ws, size_t ws_size,
                              hipStream_t stream)
{
    const float* Q   = (const float*)d_in[0];
    const float* K   = (const float*)d_in[1];
    const float* V   = (const float*)d_in[2];
    const int*  mask = (const int*) d_in[3];
    const float* Wq  = (const float*)d_in[4];
    const float* bq  = (const float*)d_in[5];
    const float* Wk  = (const float*)d_in[6];
    const float* bk  = (const float*)d_in[7];
    const float* Wv  = (const float*)d_in[8];
    const float* bv  = (const float*)d_in[9];
    float* out = (float*)d_out;

    short* qs = (short*)d_ws;                       // [B*S, D]   2 MB
    short* ks = qs + (size_t)B_ * S_ * D_;          // [B*S, D]   2 MB
    short* vT = ks + (size_t)B_ * S_ * D_;          // [B, D, S]  2 MB
    short* WT = vT + (size_t)B_ * S_ * D_;          // [3, D, E]  384 KB
    int* flag = (int*)(WT + 3 * D_ * E_);           // 4 B

    prep_kernel<<<768, 256, 0, stream>>>(Wq, Wk, Wv, WT, flag);
    proj_kernel<<<dim3(256, 3), 256, 0, stream>>>(Q, K, V, WT, bq, bk, bv,
                                                  qs, ks, vT, (const int4*)mask, flag);
    flash_kernel<<<256, 512, 0, stream>>>(qs, ks, vT, mask, flag, out);
}

// Round 4
// 345.267 us; speedup vs baseline: 1.0087x; 1.0087x over previous
//
#include <hip/hip_runtime.h>

#define B_ 4
#define S_ 4096
#define E_ 1024
#define D_ 64

typedef __attribute__((ext_vector_type(8))) short short8;
typedef __attribute__((ext_vector_type(4))) float floatx4;
typedef __attribute__((ext_vector_type(4))) unsigned int uint4v;

__device__ __forceinline__ floatx4 mfma_bf16(short8 a, short8 b, floatx4 c) {
    return __builtin_amdgcn_mfma_f32_16x16x32_bf16(a, b, c, 0, 0, 0);
}

// fp32 -> bf16 round-to-nearest-even (scalar)
__device__ __forceinline__ short f2bf(float f) {
    unsigned u = __builtin_bit_cast(unsigned, f);
    u = (u + 0x7FFFu + ((u >> 16) & 1u)) >> 16;
    return (short)u;
}

// packed pair fp32 -> bf16x2 (a low 16, b high 16), manual RNE
__device__ __forceinline__ unsigned pk2bf(float a, float b) {
    unsigned ua = __builtin_bit_cast(unsigned, a);
    unsigned ub = __builtin_bit_cast(unsigned, b);
    ua = (ua + 0x7FFFu + ((ua >> 16) & 1u)) >> 16;
    ub = (ub + 0x7FFFu + ((ub >> 16) & 1u)) & 0xFFFF0000u;
    return ua | ub;
}

// Kernel 1: convert+transpose weights fp32 [E,D] -> bf16 WT [3][D][E]; zero flag.
__global__ __launch_bounds__(256) void prep_kernel(
    const float* __restrict__ Wq, const float* __restrict__ Wk, const float* __restrict__ Wv,
    short* __restrict__ WT, int* __restrict__ flag)
{
    int tid = blockIdx.x * 256 + threadIdx.x;   // 768*256 = 196608 = 3*65536
    if (tid == 0) *flag = 0;
    int mat = tid >> 16;
    int rem = tid & 65535;
    const float* W = (mat == 0) ? Wq : ((mat == 1) ? Wk : Wv);
    int n = rem >> 10, k = rem & 1023;
    WT[mat * 65536 + n * E_ + k] = f2bf(W[k * D_ + n]);
}

// Kernel 2: fused QKV projection — TLP version.
//   R1/R2/R3 post-mortem: three different per-wave pipelines all ~100us with
//   everything idle at ~30% occupancy => the wall is exposed memory latency,
//   not pipeline depth. Lever: wave count. K-split x2 across waves (kh), 32
//   rows/block, grid (512,3) = 1536 blocks = 6 blocks/CU = 24 waves/CU (~75%).
//   Direct loads (R1-style, no LDS staging, no inline asm); LDS only for the
//   end-of-kernel K-split combine (8.7 KB). Mask check folded in.
__global__ __launch_bounds__(256, 4) void proj_kernel(
    const float* __restrict__ Qm, const float* __restrict__ Km, const float* __restrict__ Vm,
    const short* __restrict__ WT,
    const float* __restrict__ bq, const float* __restrict__ bk, const float* __restrict__ bv,
    short* __restrict__ qs, short* __restrict__ ks, short* __restrict__ vT,
    const int4* __restrict__ mask4, int* __restrict__ flag)
{
    __shared__ __align__(16) float of[32 * 68];     // 8704 B combine buffer

    const int mat = blockIdx.y;            // 0:q 1:k 2:v
    const int bx  = blockIdx.x;            // 0..511
    const int tid = threadIdx.x;
    const int wv = tid >> 6, lane = tid & 63;
    const int quad = lane >> 4, c16 = lane & 15;
    const int rt = wv & 1, kh = wv >> 1;
    const int m0 = bx * 32 + rt * 16;      // wave's 16 output rows

    const float* X    = (mat == 0) ? Qm : ((mat == 1) ? Km : Vm);
    const float* bias = (mat == 0) ? bq : ((mat == 1) ? bk : bv);
    const short* Wt   = WT + mat * 65536;

    // A: lane covers row m0+c16, cols kh*512 + it*32 + quad*8 (8 fp32/iter).
    // Quads 0..3 of a c16 tile together cover 128 contiguous bytes -> coalesced.
    const float* arow = X + (size_t)(m0 + c16) * E_ + kh * 512 + quad * 8;
    // W: frag f = rows f*16+c16 of W^T, k = kh*512 + it*32 + quad*8
    const short* wbase = Wt + (size_t)c16 * E_ + kh * 512 + quad * 8;

    floatx4 acc[4];
    #pragma unroll
    for (int f = 0; f < 4; ++f) acc[f] = (floatx4){0.f, 0.f, 0.f, 0.f};

    #pragma unroll 4
    for (int it = 0; it < 16; ++it) {
        float4 fa = *(const float4*)(arow + it * 32);
        float4 fb = *(const float4*)(arow + it * 32 + 4);
        uint4v uv;
        uv[0] = pk2bf(fa.x, fa.y); uv[1] = pk2bf(fa.z, fa.w);
        uv[2] = pk2bf(fb.x, fb.y); uv[3] = pk2bf(fb.z, fb.w);
        short8 a = __builtin_bit_cast(short8, uv);
        #pragma unroll
        for (int f = 0; f < 4; ++f) {
            short8 b = *(const short8*)(wbase + (size_t)f * 16384 + it * 32);
            acc[f] = mfma_bf16(a, b, acc[f]);
        }
    }

    // ---- K-split combine: kh=1 partials via LDS, kh=0 finishes ----
    if (kh == 1) {
        #pragma unroll
        for (int f = 0; f < 4; ++f)
            #pragma unroll
            for (int r = 0; r < 4; ++r)
                of[(rt * 16 + quad * 4 + r) * 68 + f * 16 + c16] = acc[f][r];
    }
    __syncthreads();
    if (kh == 0) {
        const float scale = (mat == 0) ? (0.125f * 1.4426950408889634f) : 1.0f;
        #pragma unroll
        for (int f = 0; f < 4; ++f) {
            float bb = bias[f * 16 + c16];
            #pragma unroll
            for (int r = 0; r < 4; ++r) {
                int m = m0 + quad * 4 + r;             // C/D: row = quad*4+r
                float v = (acc[f][r] + of[(rt * 16 + quad * 4 + r) * 68 + f * 16 + c16] + bb) * scale;
                short h = f2bf(v);
                if (mat == 0)      qs[(size_t)m * D_ + f * 16 + c16] = h;
                else if (mat == 1) ks[(size_t)m * D_ + f * 16 + c16] = h;
                else vT[((size_t)((m >> 12) * D_ + f * 16 + c16)) * S_ + (m & (S_ - 1))] = h;
            }
        }
    }

    // ---- mask check slice (64MB spread over all 1536 blocks)
    {
        int btid = (mat * 512 + bx) * 256 + tid;
        const int stride = 1536 * 256;
        int found = 0;
        for (int i = btid; i < (S_ * S_ / 4); i += stride) {
            int4 v = mask4[i];
            found |= (v.x == 0) | (v.y == 0) | (v.z == 0) | (v.w == 0);
        }
        if (found) atomicOr(flag, 1);
    }
}

// Kernel 3: flash attention v4 — TLP version.
//   v3 ran 256 blocks = 1 block/CU: every barrier + the serial softmax chain
//   fully exposed. v4: 32 q-rows/block, waves = 2 qw x 4 kw (KV quarters of
//   1024 keys), 32 iters/block, 512 blocks = 2 blocks/CU -> a second block
//   overlaps every stall; per-block serial work halves. 4-way KV partial
//   combine via LDS (same math as v3's 2-way). K staged in LDS (dbuf,
//   pitch-72), V direct from L2, V prefetch right after the barrier.
__global__ __launch_bounds__(512, 2) void flash_kernel(
    const short* __restrict__ qs, const short* __restrict__ ks,
    const short* __restrict__ vT, const int* __restrict__ mask,
    const int* __restrict__ flag, float* __restrict__ out)
{
    __shared__ __align__(16) char smem[47104];
    short* kst = (short*)smem;          // [2 dbuf][4 kw][32 rows][72] = 36864 B
    short* pst = kst + 18432;           // [8 waves][16 rows][40] = 10240 B

    const int bid = blockIdx.x;                     // 512 blocks
    const int b  = (bid & 7) >> 1;                  // batch -> XCD pair
    const int qt = ((bid >> 3) << 1) | (bid & 1);   // 0..127
    const int tid = threadIdx.x;
    const int w = tid >> 6;                         // 0..7
    const int qw = w & 1, kwq = w >> 1;             // q half / KV quarter
    const int lane = tid & 63;
    const int quad = lane >> 4, c16 = lane & 15;
    const int m0 = qt * 32 + qw * 16;

    const short* qrow = qs + (size_t)(b * S_ + m0 + c16) * D_ + quad * 8;
    short8 aq0 = *(const short8*)(qrow);
    short8 aq1 = *(const short8*)(qrow + 32);

    const short* kbase = ks + (size_t)b * S_ * D_;
    const short* vbase = vT + (size_t)b * D_ * S_ + kwq * 1024;

    // staging: waves {2q,2q+1} stage quarter q; wave covers 16 rows via 2 loads
    const int sq   = w >> 1;                         // staged quarter
    const int srow = (w & 1) * 16 + (lane >> 3);     // rows srow, srow+8
    const int schunk = lane & 7;
    const short* gstage = kbase + ((size_t)sq * 1024 + srow) * D_ + schunk * 8;
    short* lstage = kst + sq * 2304 + srow * 72 + schunk * 8;   // +buf*9216, +j*576

    floatx4 O[4];
    #pragma unroll
    for (int f = 0; f < 4; ++f) O[f] = (floatx4){0.f, 0.f, 0.f, 0.f};
    float lsum = 0.f;

    const int anyz = *flag;
    short* pw = pst + w * 640;
    short8 g0 = *(const short8*)(gstage);            // kt = 0, rows srow
    short8 g1 = *(const short8*)(gstage + 8 * D_);   //         rows srow+8

    for (int kt = 0; kt < 32; ++kt) {
        const int buf = kt & 1;
        *(short8*)(lstage + buf * 9216)           = g0;
        *(short8*)(lstage + buf * 9216 + 8 * 72)  = g1;
        short8 gn0 = g0, gn1 = g1;
        if (kt < 31) {
            gn0 = *(const short8*)(gstage + (size_t)(kt + 1) * 2048);
            gn1 = *(const short8*)(gstage + (size_t)(kt + 1) * 2048 + 8 * D_);
        }
        __syncthreads();                               // tile kt visible to all

        const int key0 = kt * 32;                      // within this quarter

        // V prefetch: addresses depend only on kt
        short8 vv[4];
        #pragma unroll
        for (int f = 0; f < 4; ++f)
            vv[f] = *(const short8*)(vbase + (size_t)(f * 16 + c16) * S_ + key0 + quad * 8);

        const short* kt_lds = kst + buf * 9216 + kwq * 2304;

        // S^T (32 keys x 16 q): A = K frags (LDS), B = Q frags
        floatx4 s[2];
        #pragma unroll
        for (int f = 0; f < 2; ++f) {
            const short* krow = kt_lds + (f * 16 + c16) * 72 + quad * 8;
            short8 ka0 = *(const short8*)(krow);
            short8 ka1 = *(const short8*)(krow + 32);
            floatx4 t = (floatx4){0.f, 0.f, 0.f, 0.f};
            t = mfma_bf16(ka0, aq0, t);
            t = mfma_bf16(ka1, aq1, t);
            s[f] = t;
        }

        if (anyz) {   // not taken for the all-ones bench mask
            #pragma unroll
            for (int f = 0; f < 2; ++f)
                #pragma unroll
                for (int r = 0; r < 4; ++r)
                    if (mask[(size_t)(m0 + c16) * S_ +
                             kwq * 1024 + key0 + f * 16 + quad * 4 + r] == 0)
                        s[f][r] = -__builtin_inff();
        }

        // P = exp2(s): per-lane row-sum (q = c16); pack to bf16, stage in LDS
        #pragma unroll
        for (int f = 0; f < 2; ++f) {
            float p0 = exp2f(s[f][0]), p1 = exp2f(s[f][1]);
            float p2 = exp2f(s[f][2]), p3 = exp2f(s[f][3]);
            lsum += (p0 + p1) + (p2 + p3);
            int2 pk = make_int2((int)pk2bf(p0, p1), (int)pk2bf(p2, p3));
            *(int2*)(pw + c16 * 40 + f * 16 + quad * 4) = pk;
        }

        // reload P in A-layout (wave-private, DS in-order => no barrier)
        short8 pa = *(const short8*)(pw + c16 * 40 + quad * 8);

        // O += P @ V_tile
        #pragma unroll
        for (int f = 0; f < 4; ++f) O[f] = mfma_bf16(pa, vv[f], O[f]);
        g0 = gn0; g1 = gn1;
    }

    // l: reduce across quads (all of a lane's s-regs share q-row c16)
    lsum += __shfl_xor(lsum, 16);
    lsum += __shfl_xor(lsum, 32);

    // combine the four KV quarters via LDS
    __syncthreads();
    float* of = (float*)smem;                  // [4][32][68] fp32 = 34816 B
    float* lw = (float*)(smem + 34816);        // [4][32]
    #pragma unroll
    for (int f = 0; f < 4; ++f)
        #pragma unroll
        for (int r = 0; r < 4; ++r)
            of[(kwq * 32 + qw * 16 + quad * 4 + r) * 68 + f * 16 + c16] = O[f][r];
    if (quad == 0) lw[kwq * 32 + qw * 16 + c16] = lsum;
    __syncthreads();

    {
        const int q = tid >> 4;                // 0..31
        const int col0 = (tid & 15) * 4;       // 0..60
        const float inv = 1.0f / (lw[q] + lw[32 + q] + lw[64 + q] + lw[96 + q]);
        float4 o = *(const float4*)&of[q * 68 + col0];
        #pragma unroll
        for (int k = 1; k < 4; ++k) {
            float4 t = *(const float4*)&of[(k * 32 + q) * 68 + col0];
            o.x += t.x; o.y += t.y; o.z += t.z; o.w += t.w;
        }
        o.x *= inv; o.y *= inv; o.z *= inv; o.w *= inv;
        *(float4*)(out + ((size_t)(b * S_ + qt * 32 + q)) * 64 + col0) = o;
    }
}

extern "C" void kernel_launch(void* const* d_in, const int* in_sizes, int n_in,
                              void* d_out, int out_size, void* d_ws, size_t ws_size,
                              hipStream_t stream)
{
    const float* Q   = (const float*)d_in[0];
    const float* K   = (const float*)d_in[1];
    const float* V   = (const float*)d_in[2];
    const int*  mask = (const int*) d_in[3];
    const float* Wq  = (const float*)d_in[4];
    const float* bq  = (const float*)d_in[5];
    const float* Wk  = (const float*)d_in[6];
    const float* bk  = (const float*)d_in[7];
    const float* Wv  = (const float*)d_in[8];
    const float* bv  = (const float*)d_in[9];
    float* out = (float*)d_out;

    short* qs = (short*)d_ws;                       // [B*S, D]   2 MB
    short* ks = qs + (size_t)B_ * S_ * D_;          // [B*S, D]   2 MB
    short* vT = ks + (size_t)B_ * S_ * D_;          // [B, D, S]  2 MB
    short* WT = vT + (size_t)B_ * S_ * D_;          // [3, D, E]  384 KB
    int* flag = (int*)(WT + 3 * D_ * E_);           // 4 B

    prep_kernel<<<768, 256, 0, stream>>>(Wq, Wk, Wv, WT, flag);
    proj_kernel<<<dim3(512, 3), 256, 0, stream>>>(Q, K, V, WT, bq, bk, bv,
                                                  qs, ks, vT, (const int4*)mask, flag);
    flash_kernel<<<512, 512, 0, stream>>>(qs, ks, vT, mask, flag, out);
}

// Round 5
// 307.770 us; speedup vs baseline: 1.1316x; 1.1218x over previous
//
#include <hip/hip_runtime.h>

#define B_ 4
#define S_ 4096
#define E_ 1024
#define D_ 64

typedef __attribute__((ext_vector_type(8))) short short8;
typedef __attribute__((ext_vector_type(4))) float floatx4;
typedef __attribute__((ext_vector_type(4))) unsigned int uint4v;

__device__ __forceinline__ floatx4 mfma_bf16(short8 a, short8 b, floatx4 c) {
    return __builtin_amdgcn_mfma_f32_16x16x32_bf16(a, b, c, 0, 0, 0);
}

// fp32 -> bf16 round-to-nearest-even (scalar)
__device__ __forceinline__ short f2bf(float f) {
    unsigned u = __builtin_bit_cast(unsigned, f);
    u = (u + 0x7FFFu + ((u >> 16) & 1u)) >> 16;
    return (short)u;
}

// packed pair fp32 -> bf16x2 (a low 16, b high 16), manual RNE
__device__ __forceinline__ unsigned pk2bf(float a, float b) {
    unsigned ua = __builtin_bit_cast(unsigned, a);
    unsigned ub = __builtin_bit_cast(unsigned, b);
    ua = (ua + 0x7FFFu + ((ua >> 16) & 1u)) >> 16;
    ub = (ub + 0x7FFFu + ((ub >> 16) & 1u)) & 0xFFFF0000u;
    return ua | ub;
}

// async global -> LDS DMA, 16 B per lane. LDS dest = wave-uniform base + lane*16
// (m104); global src is per-lane (enables swizzled staging, m173).
__device__ __forceinline__ void gload_lds16(const void* g, void* l) {
    __builtin_amdgcn_global_load_lds(
        (const __attribute__((address_space(1))) void*)g,
        (__attribute__((address_space(3))) void*)l, 16, 0, 0);
}

// Kernel 1: convert+transpose weights fp32 [E,D] -> bf16 WT [3][D][E]; zero flag.
__global__ __launch_bounds__(256) void prep_kernel(
    const float* __restrict__ Wq, const float* __restrict__ Wk, const float* __restrict__ Wv,
    short* __restrict__ WT, int* __restrict__ flag)
{
    int tid = blockIdx.x * 256 + threadIdx.x;   // 768*256 = 196608 = 3*65536
    if (tid == 0) *flag = 0;
    int mat = tid >> 16;
    int rem = tid & 65535;
    const float* W = (mat == 0) ? Wq : ((mat == 1) ? Wk : Wv);
    int n = rem >> 10, k = rem & 1023;
    WT[mat * 65536 + n * E_ + k] = f2bf(W[k * D_ + n]);
}

// Kernel 2: fused QKV projection v5 — full-line A-stream.
//   R1-R4 post-mortem: every variant read A as 16-row x (32..128 B) tile slices
//   -> 16-64 sub-line requests per instruction -> memory system request-rate
//   wall at ~1.3 TB/s regardless of pipelining (R2/R3) or occupancy (R4).
//   maskchk's contiguous stream hit 5.5 TB/s on the same chip. Fix: every A
//   load instruction is ONE contiguous 1-KB span of ONE row.
//   Structure: 4 waves = 2 rt x 2 kh, wave-autonomous (no loop barriers).
//   Wave stages its 16 rows x 256-k chunk = 16 KB via 16 gload_lds instrs
//   (one row-KB each; src granule-XOR-swizzled per row so the linear LDS
//   write gives conflict-free ds_read_b128 frag reads). Single buffer,
//   vmcnt(0) once per chunk, 2 chunks per wave. W depth-2 reg prefetch (L2).
//   V output written in flash's fragment-native tiled layout V3 (8-B stores).
__global__ __launch_bounds__(256, 2) void proj_kernel(
    const float* __restrict__ Qm, const float* __restrict__ Km, const float* __restrict__ Vm,
    const short* __restrict__ WT,
    const float* __restrict__ bq, const float* __restrict__ bk, const float* __restrict__ bv,
    short* __restrict__ qs, short* __restrict__ ks, short* __restrict__ vT,
    const int4* __restrict__ mask4, int* __restrict__ flag)
{
    __shared__ __align__(16) char smem[65536];      // 4 waves x 16 KB
    float* of = (float*)(smem + 32768);             // combine buf (waves 2-3 region)

    const int mat = blockIdx.y;            // 0:q 1:k 2:v
    const int bx  = blockIdx.x;            // 0..511
    const int tid = threadIdx.x;
    const int wv = tid >> 6, lane = tid & 63;
    const int quad = lane >> 4, c16 = lane & 15;
    const int rt = wv & 1, kh = wv >> 1;
    const int m0 = bx * 32 + rt * 16;      // wave's 16 output rows

    const float* X    = (mat == 0) ? Qm : ((mat == 1) ? Km : Vm);
    const float* bias = (mat == 0) ? bq : ((mat == 1) ? bk : bv);
    const char*  Xp   = (const char*)X;

    char* wlds = smem + wv * 16384;        // wave-private staging region

    // stage chunk c (256 k): row i -> LDS [i*1024 .. +1024), src = row m0+i,
    // byte span [kh*2048 + c*1024, +1024), lane l pulls granule l^(i&7).
    #define ASTAGE(c_) do {                                              \
        const size_t koff_ = (size_t)kh * 2048 + (size_t)(c_) * 1024;    \
        _Pragma("unroll")                                                \
        for (int i_ = 0; i_ < 16; ++i_) {                                \
            gload_lds16(Xp + (size_t)(m0 + i_) * 4096 + koff_            \
                           + (size_t)((lane ^ (i_ & 7)) << 4),           \
                        wlds + i_ * 1024);                               \
        }                                                                \
    } while (0)

    // W frags (L2-hot): global k-step n (0..15 within kh half)
    const short* wk = WT + mat * 65536 + (size_t)c16 * 1024 + quad * 8 + kh * 512;
    #define WLOADM(n_, dst_) do {                                        \
        _Pragma("unroll")                                                \
        for (int f_ = 0; f_ < 4; ++f_)                                   \
            dst_[f_] = *(const short8*)(wk + (n_) * 32 + f_ * 16384);    \
    } while (0)

    floatx4 acc[4];
    #pragma unroll
    for (int f = 0; f < 4; ++f) acc[f] = (floatx4){0.f, 0.f, 0.f, 0.f};
    short8 wA[4], wB[4];

    // frag read pointers: row c16, granules (s*8 + 2q)^swz, (s*8 + 2q+1)^swz
    const char* ardA = wlds + c16 * 1024 + (size_t)(((2 * quad)     ^ (c16 & 7)) << 4);
    const char* ardB = wlds + c16 * 1024 + (size_t)(((2 * quad + 1) ^ (c16 & 7)) << 4);

    #define ASTEP(s_, n_, W_) do {                                       \
        float4 fa_ = *(const float4*)(ardA + (s_) * 128);                \
        float4 fb_ = *(const float4*)(ardB + (s_) * 128);                \
        uint4v uv_;                                                      \
        uv_[0] = pk2bf(fa_.x, fa_.y); uv_[1] = pk2bf(fa_.z, fa_.w);      \
        uv_[2] = pk2bf(fb_.x, fb_.y); uv_[3] = pk2bf(fb_.z, fb_.w);      \
        short8 a_ = __builtin_bit_cast(short8, uv_);                     \
        _Pragma("unroll")                                                \
        for (int f_ = 0; f_ < 4; ++f_)                                   \
            acc[f_] = mfma_bf16(a_, W_[f_], acc[f_]);                    \
        if ((n_) + 2 < 16) WLOADM((n_) + 2, W_);                         \
    } while (0)

    WLOADM(0, wA);
    ASTAGE(0);
    WLOADM(1, wB);
    asm volatile("s_waitcnt vmcnt(0)" ::: "memory");   // chunk 0 staged

    ASTEP(0, 0, wA); ASTEP(1, 1, wB); ASTEP(2, 2, wA); ASTEP(3, 3, wB);
    ASTEP(4, 4, wA); ASTEP(5, 5, wB); ASTEP(6, 6, wA); ASTEP(7, 7, wB);

    asm volatile("s_waitcnt lgkmcnt(0)" ::: "memory"); // buffer reads drained
    ASTAGE(1);
    asm volatile("s_waitcnt vmcnt(0)" ::: "memory");   // chunk 1 staged

    ASTEP(0,  8, wA); ASTEP(1,  9, wB); ASTEP(2, 10, wA); ASTEP(3, 11, wB);
    ASTEP(4, 12, wA); ASTEP(5, 13, wB); ASTEP(6, 14, wA); ASTEP(7, 15, wB);

    #undef ASTAGE
    #undef WLOADM
    #undef ASTEP

    // ---- K-split combine (kh=1 partials via LDS, region reuse => barrier first)
    __syncthreads();
    if (kh == 1) {
        #pragma unroll
        for (int f = 0; f < 4; ++f)
            #pragma unroll
            for (int r = 0; r < 4; ++r)
                of[(rt * 16 + quad * 4 + r) * 68 + f * 16 + c16] = acc[f][r];
    }
    __syncthreads();
    if (kh == 0) {
        const float scale = (mat == 0) ? (0.125f * 1.4426950408889634f) : 1.0f;
        #pragma unroll
        for (int f = 0; f < 4; ++f) {
            float bb = bias[f * 16 + c16];
            if (mat == 2) {
                // V3 tiled layout: [tile=bx][frag f][lane'][j] bf16.
                // kappa = rt*16 + quad*4 + r; lane' = (kappa>>3)*16 + c16; j = kappa&7.
                float v0 = acc[0 + f][0] + of[(rt * 16 + quad * 4 + 0) * 68 + f * 16 + c16] + bb;
                float v1 = acc[f][1] + of[(rt * 16 + quad * 4 + 1) * 68 + f * 16 + c16] + bb;
                float v2 = acc[f][2] + of[(rt * 16 + quad * 4 + 2) * 68 + f * 16 + c16] + bb;
                float v3 = acc[f][3] + of[(rt * 16 + quad * 4 + 3) * 68 + f * 16 + c16] + bb;
                int2 pk = make_int2((int)pk2bf(v0, v1), (int)pk2bf(v2, v3));
                const int lane2 = (rt * 2 + (quad >> 1)) * 16 + c16;
                const int j0 = (quad & 1) * 4;
                *(int2*)(vT + ((size_t)(bx * 4 + f) * 512 + lane2 * 8 + j0)) = pk;
            } else {
                #pragma unroll
                for (int r = 0; r < 4; ++r) {
                    int m = m0 + quad * 4 + r;             // C/D: row = quad*4+r
                    float v = (acc[f][r] + of[(rt * 16 + quad * 4 + r) * 68 + f * 16 + c16] + bb) * scale;
                    short h = f2bf(v);
                    if (mat == 0) qs[(size_t)m * D_ + f * 16 + c16] = h;
                    else          ks[(size_t)m * D_ + f * 16 + c16] = h;
                }
            }
        }
    }

    // ---- mask check slice (64MB spread over all 1536 blocks, contiguous)
    {
        int btid = (mat * 512 + bx) * 256 + tid;
        const int stride = 1536 * 256;
        int found = 0;
        for (int i = btid; i < (S_ * S_ / 4); i += stride) {
            int4 v = mask4[i];
            found |= (v.x == 0) | (v.y == 0) | (v.z == 0) | (v.w == 0);
        }
        if (found) atomicOr(flag, 1);
    }
}

// Kernel 3: flash attention v5.
//   Same structure as v4 (512 blocks, 2/CU, 2 qw x 4 kwq waves, K LDS-staged
//   dbuf). Change: V is now in the fragment-native tiled layout V3
//   [tile][frag][lane][8] bf16, so each per-iter V fragment load is ONE
//   contiguous 1-KB instruction from XCD-local L2 (v4's vT reads were 64x16-B
//   scattered segments per instruction -> L2 request-rate wall).
__global__ __launch_bounds__(512, 2) void flash_kernel(
    const short* __restrict__ qs, const short* __restrict__ ks,
    const short* __restrict__ vT, const int* __restrict__ mask,
    const int* __restrict__ flag, float* __restrict__ out)
{
    __shared__ __align__(16) char smem[47104];
    short* kst = (short*)smem;          // [2 dbuf][4 kw][32 rows][72] = 36864 B
    short* pst = kst + 18432;           // [8 waves][16 rows][40] = 10240 B

    const int bid = blockIdx.x;                     // 512 blocks
    const int b  = (bid & 7) >> 1;                  // batch -> XCD pair
    const int qt = ((bid >> 3) << 1) | (bid & 1);   // 0..127
    const int tid = threadIdx.x;
    const int w = tid >> 6;                         // 0..7
    const int qw = w & 1, kwq = w >> 1;             // q half / KV quarter
    const int lane = tid & 63;
    const int quad = lane >> 4, c16 = lane & 15;
    const int m0 = qt * 32 + qw * 16;

    const short* qrow = qs + (size_t)(b * S_ + m0 + c16) * D_ + quad * 8;
    short8 aq0 = *(const short8*)(qrow);
    short8 aq1 = *(const short8*)(qrow + 32);

    const short* kbase = ks + (size_t)b * S_ * D_;
    const short* vbase = vT + (size_t)b * 262144 + (size_t)kwq * 65536;

    // staging: waves {2q,2q+1} stage quarter q; wave covers 16 rows via 2 loads
    const int sq   = w >> 1;                         // staged quarter
    const int srow = (w & 1) * 16 + (lane >> 3);     // rows srow, srow+8
    const int schunk = lane & 7;
    const short* gstage = kbase + ((size_t)sq * 1024 + srow) * D_ + schunk * 8;
    short* lstage = kst + sq * 2304 + srow * 72 + schunk * 8;   // +buf*9216

    floatx4 O[4];
    #pragma unroll
    for (int f = 0; f < 4; ++f) O[f] = (floatx4){0.f, 0.f, 0.f, 0.f};
    float lsum = 0.f;

    const int anyz = *flag;
    short* pw = pst + w * 640;
    short8 g0 = *(const short8*)(gstage);            // kt = 0, rows srow
    short8 g1 = *(const short8*)(gstage + 8 * D_);   //         rows srow+8

    for (int kt = 0; kt < 32; ++kt) {
        const int buf = kt & 1;
        *(short8*)(lstage + buf * 9216)           = g0;
        *(short8*)(lstage + buf * 9216 + 8 * 72)  = g1;
        short8 gn0 = g0, gn1 = g1;
        if (kt < 31) {
            gn0 = *(const short8*)(gstage + (size_t)(kt + 1) * 2048);
            gn1 = *(const short8*)(gstage + (size_t)(kt + 1) * 2048 + 8 * D_);
        }
        __syncthreads();                               // tile kt visible to all

        const int key0 = kt * 32;                      // within this quarter

        // V prefetch: 4 fragment loads, each 64 lanes x 16 B = 1 KB contiguous
        short8 vv[4];
        #pragma unroll
        for (int f = 0; f < 4; ++f)
            vv[f] = *(const short8*)(vbase + (size_t)kt * 2048 + f * 512 + lane * 8);

        const short* kt_lds = kst + buf * 9216 + kwq * 2304;

        // S^T (32 keys x 16 q): A = K frags (LDS), B = Q frags
        floatx4 s[2];
        #pragma unroll
        for (int f = 0; f < 2; ++f) {
            const short* krow = kt_lds + (f * 16 + c16) * 72 + quad * 8;
            short8 ka0 = *(const short8*)(krow);
            short8 ka1 = *(const short8*)(krow + 32);
            floatx4 t = (floatx4){0.f, 0.f, 0.f, 0.f};
            t = mfma_bf16(ka0, aq0, t);
            t = mfma_bf16(ka1, aq1, t);
            s[f] = t;
        }

        if (anyz) {   // not taken for the all-ones bench mask
            #pragma unroll
            for (int f = 0; f < 2; ++f)
                #pragma unroll
                for (int r = 0; r < 4; ++r)
                    if (mask[(size_t)(m0 + c16) * S_ +
                             kwq * 1024 + key0 + f * 16 + quad * 4 + r] == 0)
                        s[f][r] = -__builtin_inff();
        }

        // P = exp2(s): per-lane row-sum (q = c16); pack to bf16, stage in LDS
        #pragma unroll
        for (int f = 0; f < 2; ++f) {
            float p0 = exp2f(s[f][0]), p1 = exp2f(s[f][1]);
            float p2 = exp2f(s[f][2]), p3 = exp2f(s[f][3]);
            lsum += (p0 + p1) + (p2 + p3);
            int2 pk = make_int2((int)pk2bf(p0, p1), (int)pk2bf(p2, p3));
            *(int2*)(pw + c16 * 40 + f * 16 + quad * 4) = pk;
        }

        // reload P in A-layout (wave-private, DS in-order => no barrier)
        short8 pa = *(const short8*)(pw + c16 * 40 + quad * 8);

        // O += P @ V_tile
        #pragma unroll
        for (int f = 0; f < 4; ++f) O[f] = mfma_bf16(pa, vv[f], O[f]);
        g0 = gn0; g1 = gn1;
    }

    // l: reduce across quads (all of a lane's s-regs share q-row c16)
    lsum += __shfl_xor(lsum, 16);
    lsum += __shfl_xor(lsum, 32);

    // combine the four KV quarters via LDS
    __syncthreads();
    float* of = (float*)smem;                  // [4][32][68] fp32 = 34816 B
    float* lw = (float*)(smem + 34816);        // [4][32]
    #pragma unroll
    for (int f = 0; f < 4; ++f)
        #pragma unroll
        for (int r = 0; r < 4; ++r)
            of[(kwq * 32 + qw * 16 + quad * 4 + r) * 68 + f * 16 + c16] = O[f][r];
    if (quad == 0) lw[kwq * 32 + qw * 16 + c16] = lsum;
    __syncthreads();

    {
        const int q = tid >> 4;                // 0..31
        const int col0 = (tid & 15) * 4;       // 0..60
        const float inv = 1.0f / (lw[q] + lw[32 + q] + lw[64 + q] + lw[96 + q]);
        float4 o = *(const float4*)&of[q * 68 + col0];
        #pragma unroll
        for (int k = 1; k < 4; ++k) {
            float4 t = *(const float4*)&of[(k * 32 + q) * 68 + col0];
            o.x += t.x; o.y += t.y; o.z += t.z; o.w += t.w;
        }
        o.x *= inv; o.y *= inv; o.z *= inv; o.w *= inv;
        *(float4*)(out + ((size_t)(b * S_ + qt * 32 + q)) * 64 + col0) = o;
    }
}

extern "C" void kernel_launch(void* const* d_in, const int* in_sizes, int n_in,
                              void* d_out, int out_size, void* d_ws, size_t ws_size,
                              hipStream_t stream)
{
    const float* Q   = (const float*)d_in[0];
    const float* K   = (const float*)d_in[1];
    const float* V   = (const float*)d_in[2];
    const int*  mask = (const int*) d_in[3];
    const float* Wq  = (const float*)d_in[4];
    const float* bq  = (const float*)d_in[5];
    const float* Wk  = (const float*)d_in[6];
    const float* bk  = (const float*)d_in[7];
    const float* Wv  = (const float*)d_in[8];
    const float* bv  = (const float*)d_in[9];
    float* out = (float*)d_out;

    short* qs = (short*)d_ws;                       // [B*S, D]   2 MB
    short* ks = qs + (size_t)B_ * S_ * D_;          // [B*S, D]   2 MB
    short* vT = ks + (size_t)B_ * S_ * D_;          // V3 tiled   2 MB
    short* WT = vT + (size_t)B_ * S_ * D_;          // [3, D, E]  384 KB
    int* flag = (int*)(WT + 3 * D_ * E_);           // 4 B

    prep_kernel<<<768, 256, 0, stream>>>(Wq, Wk, Wv, WT, flag);
    proj_kernel<<<dim3(512, 3), 256, 0, stream>>>(Q, K, V, WT, bq, bk, bv,
                                                  qs, ks, vT, (const int4*)mask, flag);
    flash_kernel<<<512, 512, 0, stream>>>(qs, ks, vT, mask, flag, out);
}

// Round 8
// 297.358 us; speedup vs baseline: 1.1712x; 1.0350x over previous
//
#include <hip/hip_runtime.h>

#define B_ 4
#define S_ 4096
#define E_ 1024
#define D_ 64

typedef __attribute__((ext_vector_type(8))) short short8;
typedef __attribute__((ext_vector_type(4))) float floatx4;
typedef __attribute__((ext_vector_type(4))) unsigned int uint4v;
typedef __attribute__((ext_vector_type(4))) int intx4;

__device__ __forceinline__ floatx4 mfma_bf16(short8 a, short8 b, floatx4 c) {
    return __builtin_amdgcn_mfma_f32_16x16x32_bf16(a, b, c, 0, 0, 0);
}

// fp32 -> bf16 round-to-nearest-even (scalar)
__device__ __forceinline__ short f2bf(float f) {
    unsigned u = __builtin_bit_cast(unsigned, f);
    u = (u + 0x7FFFu + ((u >> 16) & 1u)) >> 16;
    return (short)u;
}

// packed pair fp32 -> bf16x2 (a low 16, b high 16), manual RNE
__device__ __forceinline__ unsigned pk2bf(float a, float b) {
    unsigned ua = __builtin_bit_cast(unsigned, a);
    unsigned ub = __builtin_bit_cast(unsigned, b);
    ua = (ua + 0x7FFFu + ((ua >> 16) & 1u)) >> 16;
    ub = (ub + 0x7FFFu + ((ub >> 16) & 1u)) & 0xFFFF0000u;
    return ua | ub;
}

// async global -> LDS DMA, 16 B per lane, NON-TEMPORAL (aux=2 -> NT CPol bit:
// no L2/L3 allocate). A-stream is read-once per iteration; the 256-MB input set
// exactly equals L3 capacity and is re-poisoned every iteration, so cached A
// reads thrash the Infinity Cache (R5 evidence: FETCH 132 MB of 256 MB demand,
// both HBM and L3 paths far under ceiling).
__device__ __forceinline__ void gload_lds16_nt(const void* g, void* l) {
    __builtin_amdgcn_global_load_lds(
        (const __attribute__((address_space(1))) void*)g,
        (__attribute__((address_space(3))) void*)l, 16, 0, 2);
}

// Kernel 1: convert+transpose weights fp32 [E,D] -> bf16 WT [3][D][E]; zero flag.
__global__ __launch_bounds__(256) void prep_kernel(
    const float* __restrict__ Wq, const float* __restrict__ Wk, const float* __restrict__ Wv,
    short* __restrict__ WT, int* __restrict__ flag)
{
    int tid = blockIdx.x * 256 + threadIdx.x;   // 768*256 = 196608 = 3*65536
    if (tid == 0) *flag = 0;
    int mat = tid >> 16;
    int rem = tid & 65535;
    const float* W = (mat == 0) ? Wq : ((mat == 1) ? Wk : Wv);
    int n = rem >> 10, k = rem & 1023;
    WT[mat * 65536 + n * E_ + k] = f2bf(W[k * D_ + n]);
}

// Kernel 2: fused QKV projection v6 — non-temporal A-stream.
//   v5 post-mortem: 1-KB-contiguous DMA didn't move the ~2.3 TB/s demand wall;
//   FETCH(132MB) vs demand(256MB) says half the stream churns through L3 whose
//   allocate/evict path is the serializer (inputs = 256 MB = L3 size, rewritten
//   every iteration). Fix: A + mask reads are non-temporal (read-once data);
//   W / outputs stay cached (reused by flash).
//   Structure: 4 waves = 2 rt x 2 kh, wave-autonomous. 4 chunks of 8 KB per
//   wave (16 rows x 128 k), each staged by 8 NT gload_lds (2 rows / instr,
//   512-B contiguous per row, granule-XOR pre-swizzled src so linear LDS holds
//   conflict-free ds_read_b128 frags). 32 KB LDS -> 4 blocks/CU, 16 waves/CU.
__global__ __launch_bounds__(256, 4) void proj_kernel(
    const float* __restrict__ Qm, const float* __restrict__ Km, const float* __restrict__ Vm,
    const short* __restrict__ WT,
    const float* __restrict__ bq, const float* __restrict__ bk, const float* __restrict__ bv,
    short* __restrict__ qs, short* __restrict__ ks, short* __restrict__ vT,
    const int* __restrict__ maskp, int* __restrict__ flag)
{
    __shared__ __align__(16) char smem[32768];      // 4 waves x 8 KB
    float* of = (float*)(smem + 16384);             // combine buf (waves 2-3 region)

    const int mat = blockIdx.y;            // 0:q 1:k 2:v
    const int bx  = blockIdx.x;            // 0..511
    const int tid = threadIdx.x;
    const int wv = tid >> 6, lane = tid & 63;
    const int quad = lane >> 4, c16 = lane & 15;
    const int rt = wv & 1, kh = wv >> 1;
    const int m0 = bx * 32 + rt * 16;      // wave's 16 output rows

    const float* X    = (mat == 0) ? Qm : ((mat == 1) ? Km : Vm);
    const float* bias = (mat == 0) ? bq : ((mat == 1) ? bk : bv);
    const char*  Xp   = (const char*)X;

    char* wlds = smem + wv * 8192;         // wave-private staging region

    // stage chunk c (128 k = 512 B/row): instr j covers rows 2j, 2j+1.
    // lane l: row 2j+(l>>5), granule g=l&31 holds global granule g^(row&7).
    const int srow2 = lane >> 5;                   // 0/1 within row pair
    const int sg    = lane & 31;
    #define ASTAGE(c_) do {                                                   \
        const size_t koff_ = (size_t)kh * 2048 + (size_t)(c_) * 512;          \
        _Pragma("unroll")                                                     \
        for (int j_ = 0; j_ < 8; ++j_) {                                      \
            const int row_ = 2 * j_ + srow2;                                  \
            gload_lds16_nt(Xp + (size_t)(m0 + row_) * 4096 + koff_            \
                              + (size_t)((sg ^ (row_ & 7)) << 4),             \
                           wlds + j_ * 1024);                                 \
        }                                                                     \
    } while (0)

    // W frags (L2-hot): global k-step n (0..15 within kh half)
    const short* wk = WT + mat * 65536 + (size_t)c16 * 1024 + quad * 8 + kh * 512;
    #define WLOADM(n_, dst_) do {                                             \
        _Pragma("unroll")                                                     \
        for (int f_ = 0; f_ < 4; ++f_)                                        \
            dst_[f_] = *(const short8*)(wk + (n_) * 32 + f_ * 16384);         \
    } while (0)

    floatx4 acc[4];
    #pragma unroll
    for (int f = 0; f < 4; ++f) acc[f] = (floatx4){0.f, 0.f, 0.f, 0.f};
    short8 wA[4], wB[4];

    // frag read: row c16, granules (s*8+2q)^(c16&7), (s*8+2q+1)^(c16&7)
    const char* ardA = wlds + c16 * 512 + (size_t)(((2 * quad)     ^ (c16 & 7)) << 4);
    const char* ardB = wlds + c16 * 512 + (size_t)(((2 * quad + 1) ^ (c16 & 7)) << 4);

    #define ASTEP(s_, n_, W_) do {                                            \
        float4 fa_ = *(const float4*)(ardA + (s_) * 128);                     \
        float4 fb_ = *(const float4*)(ardB + (s_) * 128);                     \
        uint4v uv_;                                                           \
        uv_[0] = pk2bf(fa_.x, fa_.y); uv_[1] = pk2bf(fa_.z, fa_.w);           \
        uv_[2] = pk2bf(fb_.x, fb_.y); uv_[3] = pk2bf(fb_.z, fb_.w);           \
        short8 a_ = __builtin_bit_cast(short8, uv_);                          \
        _Pragma("unroll")                                                     \
        for (int f_ = 0; f_ < 4; ++f_)                                        \
            acc[f_] = mfma_bf16(a_, W_[f_], acc[f_]);                         \
        if ((n_) + 2 < 16) WLOADM((n_) + 2, W_);                              \
    } while (0)

    ASTAGE(0);
    WLOADM(0, wA); WLOADM(1, wB);
    asm volatile("s_waitcnt vmcnt(0)" ::: "memory");

    ASTEP(0, 0, wA); ASTEP(1, 1, wB); ASTEP(2, 2, wA); ASTEP(3, 3, wB);
    asm volatile("s_waitcnt lgkmcnt(0)" ::: "memory");
    ASTAGE(1);
    asm volatile("s_waitcnt vmcnt(0)" ::: "memory");

    ASTEP(0, 4, wA); ASTEP(1, 5, wB); ASTEP(2, 6, wA); ASTEP(3, 7, wB);
    asm volatile("s_waitcnt lgkmcnt(0)" ::: "memory");
    ASTAGE(2);
    asm volatile("s_waitcnt vmcnt(0)" ::: "memory");

    ASTEP(0, 8, wA); ASTEP(1, 9, wB); ASTEP(2, 10, wA); ASTEP(3, 11, wB);
    asm volatile("s_waitcnt lgkmcnt(0)" ::: "memory");
    ASTAGE(3);
    asm volatile("s_waitcnt vmcnt(0)" ::: "memory");

    ASTEP(0, 12, wA); ASTEP(1, 13, wB); ASTEP(2, 14, wA); ASTEP(3, 15, wB);

    #undef ASTAGE
    #undef WLOADM
    #undef ASTEP

    // ---- K-split combine (kh=1 partials via LDS, region reuse => barrier first)
    __syncthreads();
    if (kh == 1) {
        #pragma unroll
        for (int f = 0; f < 4; ++f)
            #pragma unroll
            for (int r = 0; r < 4; ++r)
                of[(rt * 16 + quad * 4 + r) * 68 + f * 16 + c16] = acc[f][r];
    }
    __syncthreads();
    if (kh == 0) {
        const float scale = (mat == 0) ? (0.125f * 1.4426950408889634f) : 1.0f;
        #pragma unroll
        for (int f = 0; f < 4; ++f) {
            float bb = bias[f * 16 + c16];
            if (mat == 2) {
                // V3 tiled layout: [tile=bx][frag f][lane'][j] bf16.
                float v0 = acc[f][0] + of[(rt * 16 + quad * 4 + 0) * 68 + f * 16 + c16] + bb;
                float v1 = acc[f][1] + of[(rt * 16 + quad * 4 + 1) * 68 + f * 16 + c16] + bb;
                float v2 = acc[f][2] + of[(rt * 16 + quad * 4 + 2) * 68 + f * 16 + c16] + bb;
                float v3 = acc[f][3] + of[(rt * 16 + quad * 4 + 3) * 68 + f * 16 + c16] + bb;
                int2 pk = make_int2((int)pk2bf(v0, v1), (int)pk2bf(v2, v3));
                const int lane2 = (rt * 2 + (quad >> 1)) * 16 + c16;
                const int j0 = (quad & 1) * 4;
                *(int2*)(vT + ((size_t)(bx * 4 + f) * 512 + lane2 * 8 + j0)) = pk;
            } else {
                #pragma unroll
                for (int r = 0; r < 4; ++r) {
                    int m = m0 + quad * 4 + r;             // C/D: row = quad*4+r
                    float v = (acc[f][r] + of[(rt * 16 + quad * 4 + r) * 68 + f * 16 + c16] + bb) * scale;
                    short h = f2bf(v);
                    if (mat == 0) qs[(size_t)m * D_ + f * 16 + c16] = h;
                    else          ks[(size_t)m * D_ + f * 16 + c16] = h;
                }
            }
        }
    }

    // ---- mask check slice (64MB over 1536 blocks, contiguous, NON-TEMPORAL)
    {
        int btid = (mat * 512 + bx) * 256 + tid;
        const int stride = 1536 * 256;
        int found = 0;
        const intx4* m4 = (const intx4*)maskp;
        for (int i = btid; i < (S_ * S_ / 4); i += stride) {
            intx4 v = __builtin_nontemporal_load(m4 + i);
            found |= (v.x == 0) | (v.y == 0) | (v.z == 0) | (v.w == 0);
        }
        if (found) atomicOr(flag, 1);
    }
}

// Kernel 3: flash attention v5 (unchanged — V3 layout win banked in R5).
__global__ __launch_bounds__(512, 2) void flash_kernel(
    const short* __restrict__ qs, const short* __restrict__ ks,
    const short* __restrict__ vT, const int* __restrict__ mask,
    const int* __restrict__ flag, float* __restrict__ out)
{
    __shared__ __align__(16) char smem[47104];
    short* kst = (short*)smem;          // [2 dbuf][4 kw][32 rows][72] = 36864 B
    short* pst = kst + 18432;           // [8 waves][16 rows][40] = 10240 B

    const int bid = blockIdx.x;                     // 512 blocks
    const int b  = (bid & 7) >> 1;                  // batch -> XCD pair
    const int qt = ((bid >> 3) << 1) | (bid & 1);   // 0..127
    const int tid = threadIdx.x;
    const int w = tid >> 6;                         // 0..7
    const int qw = w & 1, kwq = w >> 1;             // q half / KV quarter
    const int lane = tid & 63;
    const int quad = lane >> 4, c16 = lane & 15;
    const int m0 = qt * 32 + qw * 16;

    const short* qrow = qs + (size_t)(b * S_ + m0 + c16) * D_ + quad * 8;
    short8 aq0 = *(const short8*)(qrow);
    short8 aq1 = *(const short8*)(qrow + 32);

    const short* kbase = ks + (size_t)b * S_ * D_;
    const short* vbase = vT + (size_t)b * 262144 + (size_t)kwq * 65536;

    // staging: waves {2q,2q+1} stage quarter q; wave covers 16 rows via 2 loads
    const int sq   = w >> 1;                         // staged quarter
    const int srow = (w & 1) * 16 + (lane >> 3);     // rows srow, srow+8
    const int schunk = lane & 7;
    const short* gstage = kbase + ((size_t)sq * 1024 + srow) * D_ + schunk * 8;
    short* lstage = kst + sq * 2304 + srow * 72 + schunk * 8;   // +buf*9216

    floatx4 O[4];
    #pragma unroll
    for (int f = 0; f < 4; ++f) O[f] = (floatx4){0.f, 0.f, 0.f, 0.f};
    float lsum = 0.f;

    const int anyz = *flag;
    short* pw = pst + w * 640;
    short8 g0 = *(const short8*)(gstage);            // kt = 0, rows srow
    short8 g1 = *(const short8*)(gstage + 8 * D_);   //         rows srow+8

    for (int kt = 0; kt < 32; ++kt) {
        const int buf = kt & 1;
        *(short8*)(lstage + buf * 9216)           = g0;
        *(short8*)(lstage + buf * 9216 + 8 * 72)  = g1;
        short8 gn0 = g0, gn1 = g1;
        if (kt < 31) {
            gn0 = *(const short8*)(gstage + (size_t)(kt + 1) * 2048);
            gn1 = *(const short8*)(gstage + (size_t)(kt + 1) * 2048 + 8 * D_);
        }
        __syncthreads();                               // tile kt visible to all

        const int key0 = kt * 32;                      // within this quarter

        // V prefetch: 4 fragment loads, each 64 lanes x 16 B = 1 KB contiguous
        short8 vv[4];
        #pragma unroll
        for (int f = 0; f < 4; ++f)
            vv[f] = *(const short8*)(vbase + (size_t)kt * 2048 + f * 512 + lane * 8);

        const short* kt_lds = kst + buf * 9216 + kwq * 2304;

        // S^T (32 keys x 16 q): A = K frags (LDS), B = Q frags
        floatx4 s[2];
        #pragma unroll
        for (int f = 0; f < 2; ++f) {
            const short* krow = kt_lds + (f * 16 + c16) * 72 + quad * 8;
            short8 ka0 = *(const short8*)(krow);
            short8 ka1 = *(const short8*)(krow + 32);
            floatx4 t = (floatx4){0.f, 0.f, 0.f, 0.f};
            t = mfma_bf16(ka0, aq0, t);
            t = mfma_bf16(ka1, aq1, t);
            s[f] = t;
        }

        if (anyz) {   // not taken for the all-ones bench mask
            #pragma unroll
            for (int f = 0; f < 2; ++f)
                #pragma unroll
                for (int r = 0; r < 4; ++r)
                    if (mask[(size_t)(m0 + c16) * S_ +
                             kwq * 1024 + key0 + f * 16 + quad * 4 + r] == 0)
                        s[f][r] = -__builtin_inff();
        }

        // P = exp2(s): per-lane row-sum (q = c16); pack to bf16, stage in LDS
        #pragma unroll
        for (int f = 0; f < 2; ++f) {
            float p0 = exp2f(s[f][0]), p1 = exp2f(s[f][1]);
            float p2 = exp2f(s[f][2]), p3 = exp2f(s[f][3]);
            lsum += (p0 + p1) + (p2 + p3);
            int2 pk = make_int2((int)pk2bf(p0, p1), (int)pk2bf(p2, p3));
            *(int2*)(pw + c16 * 40 + f * 16 + quad * 4) = pk;
        }

        // reload P in A-layout (wave-private, DS in-order => no barrier)
        short8 pa = *(const short8*)(pw + c16 * 40 + quad * 8);

        // O += P @ V_tile
        #pragma unroll
        for (int f = 0; f < 4; ++f) O[f] = mfma_bf16(pa, vv[f], O[f]);
        g0 = gn0; g1 = gn1;
    }

    // l: reduce across quads (all of a lane's s-regs share q-row c16)
    lsum += __shfl_xor(lsum, 16);
    lsum += __shfl_xor(lsum, 32);

    // combine the four KV quarters via LDS
    __syncthreads();
    float* of = (float*)smem;                  // [4][32][68] fp32 = 34816 B
    float* lw = (float*)(smem + 34816);        // [4][32]
    #pragma unroll
    for (int f = 0; f < 4; ++f)
        #pragma unroll
        for (int r = 0; r < 4; ++r)
            of[(kwq * 32 + qw * 16 + quad * 4 + r) * 68 + f * 16 + c16] = O[f][r];
    if (quad == 0) lw[kwq * 32 + qw * 16 + c16] = lsum;
    __syncthreads();

    {
        const int q = tid >> 4;                // 0..31
        const int col0 = (tid & 15) * 4;       // 0..60
        const float inv = 1.0f / (lw[q] + lw[32 + q] + lw[64 + q] + lw[96 + q]);
        float4 o = *(const float4*)&of[q * 68 + col0];
        #pragma unroll
        for (int k = 1; k < 4; ++k) {
            float4 t = *(const float4*)&of[(k * 32 + q) * 68 + col0];
            o.x += t.x; o.y += t.y; o.z += t.z; o.w += t.w;
        }
        o.x *= inv; o.y *= inv; o.z *= inv; o.w *= inv;
        *(float4*)(out + ((size_t)(b * S_ + qt * 32 + q)) * 64 + col0) = o;
    }
}

extern "C" void kernel_launch(void* const* d_in, const int* in_sizes, int n_in,
                              void* d_out, int out_size, void* d_ws, size_t ws_size,
                              hipStream_t stream)
{
    const float* Q   = (const float*)d_in[0];
    const float* K   = (const float*)d_in[1];
    const float* V   = (const float*)d_in[2];
    const int*  mask = (const int*) d_in[3];
    const float* Wq  = (const float*)d_in[4];
    const float* bq  = (const float*)d_in[5];
    const float* Wk  = (const float*)d_in[6];
    const float* bk  = (const float*)d_in[7];
    const float* Wv  = (const float*)d_in[8];
    const float* bv  = (const float*)d_in[9];
    float* out = (float*)d_out;

    short* qs = (short*)d_ws;                       // [B*S, D]   2 MB
    short* ks = qs + (size_t)B_ * S_ * D_;          // [B*S, D]   2 MB
    short* vT = ks + (size_t)B_ * S_ * D_;          // V3 tiled   2 MB
    short* WT = vT + (size_t)B_ * S_ * D_;          // [3, D, E]  384 KB
    int* flag = (int*)(WT + 3 * D_ * E_);           // 4 B

    prep_kernel<<<768, 256, 0, stream>>>(Wq, Wk, Wv, WT, flag);
    proj_kernel<<<dim3(512, 3), 256, 0, stream>>>(Q, K, V, WT, bq, bk, bv,
                                                  qs, ks, vT, mask, flag);
    flash_kernel<<<512, 512, 0, stream>>>(qs, ks, vT, mask, flag, out);
}